// Round 1
// baseline (185.560 us; speedup 1.0000x reference)
//
#include <hip/hip_runtime.h>

#define NUM_TABLES 26
#define VOCAB      100000
#define EMB_DIM    128
#define BATCH      8192
#define HOTNESS    10

// One 32-lane group per output row (t,b): each lane holds one float4 (4 of the
// 128 dims). 10 gathers of 512B contiguous each, accumulate f32, scale, store.
__global__ __launch_bounds__(256) void sok_emb_kernel(
    const int* __restrict__ ids,
    const float* __restrict__ tables,
    float* __restrict__ out)
{
    const int rowsPerBlock = 256 / 32;                 // 8 (t,b) rows per block
    int r    = blockIdx.x * rowsPerBlock + (threadIdx.x >> 5);
    int lane = threadIdx.x & 31;

    int t = r / BATCH;
    int b = r - t * BATCH;
    if (t >= NUM_TABLES) return;

    const int* idp = ids + ((size_t)t * BATCH + b) * HOTNESS;
    const float4* tbl = reinterpret_cast<const float4*>(tables)
                      + (size_t)t * VOCAB * (EMB_DIM / 4);

    // Load all 10 indices first so the compiler can issue the 10 gathers
    // back-to-back (latency hiding via vmcnt overlap).
    int idx[HOTNESS];
    #pragma unroll
    for (int h = 0; h < HOTNESS; ++h) idx[h] = idp[h];

    float4 acc = make_float4(0.f, 0.f, 0.f, 0.f);
    #pragma unroll
    for (int h = 0; h < HOTNESS; ++h) {
        float4 v = tbl[(size_t)idx[h] * (EMB_DIM / 4) + lane];
        acc.x += v.x; acc.y += v.y; acc.z += v.z; acc.w += v.w;
    }

    const float s = 1.0f / (float)HOTNESS;
    acc.x *= s; acc.y *= s; acc.z *= s; acc.w *= s;

    float4* op = reinterpret_cast<float4*>(out)
               + ((size_t)b * NUM_TABLES + t) * (EMB_DIM / 4) + lane;
    *op = acc;
}

extern "C" void kernel_launch(void* const* d_in, const int* in_sizes, int n_in,
                              void* d_out, int out_size, void* d_ws, size_t ws_size,
                              hipStream_t stream) {
    const int*   ids    = (const int*)d_in[0];
    const float* tables = (const float*)d_in[1];
    float*       out    = (float*)d_out;

    const int totalRows = NUM_TABLES * BATCH;          // 212992
    const int rowsPerBlock = 256 / 32;                 // 8
    dim3 grid((totalRows + rowsPerBlock - 1) / rowsPerBlock);
    sok_emb_kernel<<<grid, 256, 0, stream>>>(ids, tables, out);
}